// Round 1
// baseline (632.372 us; speedup 1.0000x reference)
//
#include <hip/hip_runtime.h>
#include <math.h>

// Volume geometry (1,1,96,128,128)
#define DIMD 96
#define DIMH 128
#define DIMW 128
#define N_ELEM (DIMD*DIMH*DIMW)   // 1,572,864

// Pool tile
constexpr int TX = 32, TY = 8, TZ = 8;
constexpr int LX = TX + 2, LY = TY + 2, LZ = TZ + 2;  // 34,10,10
constexpr int ZTILES = DIMD / TZ;                      // 12

#define RBLOCKS 1024

__device__ __forceinline__ float sigmoidf_(float x) { return 1.0f / (1.0f + expf(-x)); }

// img[0..N)   = sigmoid(sigmoid(y_pred))   (input to skel_pred)
// img[N..2N)  = y_true                     (input to skel_true)
__global__ __launch_bounds__(256) void prologue_kernel(const float* __restrict__ yp,
                                                       const float* __restrict__ yt,
                                                       float* __restrict__ img) {
    int i = blockIdx.x * 256 + threadIdx.x;
    if (i < N_ELEM) {
        img[i]          = sigmoidf_(sigmoidf_(yp[i]));
        img[N_ELEM + i] = yt[i];
    }
}

// 3x3x3 min/max pool, SAME padding (clamp-to-edge == skip-OOB for min/max).
// Batched over 2 volumes via blockIdx.z.
// OP: 0 = min (erode), 1 = max (dilate)
// EPI: 0 = dst[i] = acc
//      1 = skel[i] = relu(img[i] - acc)                       (skeleton init)
//      2 = d = relu(img[i]-acc); skel[i] += relu(d - skel*d)  (skeleton update)
template<int OP, int EPI>
__global__ __launch_bounds__(256) void pool_kernel(const float* __restrict__ src,
                                                   float* __restrict__ dst,
                                                   const float* __restrict__ img,
                                                   float* __restrict__ skel) {
    __shared__ float t[LZ][LY][LX];
    const int b    = blockIdx.z / ZTILES;
    const int zb   = blockIdx.z - b * ZTILES;
    const int base = b * N_ELEM;
    const int bx = blockIdx.x * TX, by = blockIdx.y * TY, bz = zb * TZ;

    const float* s = src + base;
    for (int f = threadIdx.x; f < LZ * LY * LX; f += 256) {
        int lz = f / (LY * LX);
        int r  = f - lz * (LY * LX);
        int ly = r / LX;
        int lx = r - ly * LX;
        int gz = min(max(bz + lz - 1, 0), DIMD - 1);
        int gy = min(max(by + ly - 1, 0), DIMH - 1);
        int gx = min(max(bx + lx - 1, 0), DIMW - 1);
        t[lz][ly][lx] = s[(gz * DIMH + gy) * DIMW + gx];
    }
    __syncthreads();

    const int tx = threadIdx.x & 31;
    const int ty = threadIdx.x >> 5;
    #pragma unroll
    for (int tz = 0; tz < TZ; ++tz) {
        float acc = OP ? -INFINITY : INFINITY;
        #pragma unroll
        for (int dz = 0; dz < 3; ++dz)
            #pragma unroll
            for (int dy = 0; dy < 3; ++dy)
                #pragma unroll
                for (int dx = 0; dx < 3; ++dx) {
                    float v = t[tz + dz][ty + dy][tx + dx];
                    acc = OP ? fmaxf(acc, v) : fminf(acc, v);
                }
        const int gi = base + ((bz + tz) * DIMH + (by + ty)) * DIMW + (bx + tx);
        if (EPI == 0) {
            dst[gi] = acc;
        } else if (EPI == 1) {
            skel[gi] = fmaxf(img[gi] - acc, 0.0f);
        } else {
            float d = fmaxf(img[gi] - acc, 0.0f);
            float sk = skel[gi];
            skel[gi] = sk + fmaxf(d - sk * d, 0.0f);
        }
    }
}

__device__ __forceinline__ double wave_block_reduce(double v, double* red4) {
    // wave(64) shuffle reduce, then cross-wave via LDS (4 waves / 256 threads)
    for (int off = 32; off > 0; off >>= 1) v += __shfl_down(v, off, 64);
    int wid = threadIdx.x >> 6, lane = threadIdx.x & 63;
    if (lane == 0) red4[wid] = v;
    __syncthreads();
    double r = red4[0] + red4[1] + red4[2] + red4[3];
    __syncthreads();
    return r;  // valid in all threads
}

// 10 sums:
// 0: skel_pred*y_true  1: skel_pred  2: skel_true*s2  3: skel_true
// 4: w*s1*y_true       5: w*s1       6: w*y_true      (w = exp(-skel_true^2/2))
// 7: s1*y_true         8: s1         9: y_true
__global__ __launch_bounds__(256) void reduce_partial(const float* __restrict__ yp,
                                                      const float* __restrict__ yt,
                                                      const float* __restrict__ sp,
                                                      const float* __restrict__ st,
                                                      double* __restrict__ partials) {
    double acc[10];
    #pragma unroll
    for (int k = 0; k < 10; ++k) acc[k] = 0.0;

    for (int i = blockIdx.x * 256 + threadIdx.x; i < N_ELEM; i += RBLOCKS * 256) {
        float x  = yp[i];
        float s1 = sigmoidf_(x);
        float s2 = sigmoidf_(s1);
        float t  = yt[i];
        float a  = sp[i];
        float b  = st[i];
        float w  = expf(-0.5f * b * b);
        acc[0] += (double)(a * t);
        acc[1] += (double)a;
        acc[2] += (double)(b * s2);
        acc[3] += (double)b;
        acc[4] += (double)(w * s1 * t);
        acc[5] += (double)(w * s1);
        acc[6] += (double)(w * t);
        acc[7] += (double)(s1 * t);
        acc[8] += (double)s1;
        acc[9] += (double)t;
    }

    __shared__ double red4[4];
    #pragma unroll
    for (int k = 0; k < 10; ++k) {
        double r = wave_block_reduce(acc[k], red4);
        if (threadIdx.x == 0) partials[blockIdx.x * 10 + k] = r;
        __syncthreads();
    }
}

__global__ __launch_bounds__(256) void finalize_kernel(const double* __restrict__ partials,
                                                       float* __restrict__ out) {
    __shared__ double sums[10];
    __shared__ double red4[4];
    for (int k = 0; k < 10; ++k) {
        double v = 0.0;
        for (int j = threadIdx.x; j < RBLOCKS; j += 256) v += partials[j * 10 + k];
        double r = wave_block_reduce(v, red4);
        if (threadIdx.x == 0) sums[k] = r;
        __syncthreads();
    }
    if (threadIdx.x == 0) {
        double S0 = sums[0], S1 = sums[1], S2 = sums[2], S3 = sums[3];
        double S4 = sums[4], S5 = sums[5], S6 = sums[6];
        double S7 = sums[7], S8 = sums[8], S9 = sums[9];
        double tprec = (S0 + 1.0) / (S1 + 1.0);
        double tsens = (S2 + 1.0) / (S3 + 1.0);
        double cldice = 1.0 - 2.0 * (tprec * tsens) / (tprec + tsens + 1.0);
        double boundary = 1.0 - (2.0 * S4 + 1.0) / (S5 + S6 + 1.0);
        double dice = 1.0 - (2.0 * S7 + 1.0) / (S8 + S9 + 1.0);
        out[0] = (float)(0.5 * cldice + 0.3 * boundary + 0.2 * dice);
    }
}

extern "C" void kernel_launch(void* const* d_in, const int* in_sizes, int n_in,
                              void* d_out, int out_size, void* d_ws, size_t ws_size,
                              hipStream_t stream) {
    const float* y_pred = (const float*)d_in[0];
    const float* y_true = (const float*)d_in[1];
    float* out = (float*)d_out;

    const size_t NB = (size_t)2 * N_ELEM;  // batched (pred, true)
    float* img  = (float*)d_ws;
    float* A    = img + NB;
    float* skel = A + NB;
    double* partials = (double*)(skel + NB);

    dim3 pg(DIMW / TX, DIMH / TY, ZTILES * 2);  // (4,16,24), batch folded into z
    dim3 pb(256);

    prologue_kernel<<<(N_ELEM + 255) / 256, 256, 0, stream>>>(y_pred, y_true, img);

    // skel = relu(img - open(img));  open = dilate(erode(img))
    pool_kernel<0, 0><<<pg, pb, 0, stream>>>(img, A, nullptr, nullptr);   // erode -> A
    pool_kernel<1, 1><<<pg, pb, 0, stream>>>(A, nullptr, img, skel);      // dilate(A), init skel

    for (int it = 0; it < 16; ++it) {
        // img = erode(img)
        pool_kernel<0, 0><<<pg, pb, 0, stream>>>(img, A, nullptr, nullptr);
        { float* tmp = img; img = A; A = tmp; }
        // open(img) = dilate(erode(img)); fused skel update on store
        pool_kernel<0, 0><<<pg, pb, 0, stream>>>(img, A, nullptr, nullptr);  // erode -> A
        pool_kernel<1, 2><<<pg, pb, 0, stream>>>(A, nullptr, img, skel);     // dilate + update
    }

    float* skel_pred = skel;
    float* skel_true = skel + N_ELEM;
    reduce_partial<<<RBLOCKS, 256, 0, stream>>>(y_pred, y_true, skel_pred, skel_true, partials);
    finalize_kernel<<<1, 256, 0, stream>>>(partials, out);
}